// Round 2
// baseline (1734.312 us; speedup 1.0000x reference)
//
#include <hip/hip_runtime.h>
#include <stdint.h>

// SpikeAttention on MI355X (gfx950).
// xs/q/k/v are ms_act-quantized (multiples of 0.25 in [0,1]) -> EXACT in bf16.
// Weights split into hi+lo bf16 (residual ~2^-18) -> bf16 MFMA GEMMs at fp32-grade accuracy.
// kv = k^T v per head exactly representable in fp32 -> atomicAdd reduction exact+deterministic.
// out = q @ U with U[h,d,j] = SCALE * sum_e kv[h,d,e]*Wp[j,h*64+e].
//
// GEMM: 8-phase-family schedule (T2 swizzle + T3/T4 counted vmcnt + T5 setprio):
// BM=256 BN=128 BK=32, ring-of-4 LDS slabs (128 KiB), prefetch 3 slabs ahead,
// steady-state s_waitcnt vmcnt(8) (never 0), one barrier per phase, 32 MFMA/phase/wave.

typedef __attribute__((ext_vector_type(8))) __bf16 bf16x8;
typedef __attribute__((ext_vector_type(4))) float f32x4;

__device__ __forceinline__ float bf2f(unsigned short u) {
  return __builtin_bit_cast(float, (unsigned int)u << 16);
}
__device__ __forceinline__ unsigned short f2bf(float f) {
  unsigned int u = __builtin_bit_cast(unsigned int, f);
  u += 0x7FFFu + ((u >> 16) & 1u);
  return (unsigned short)(u >> 16);
}
__device__ __forceinline__ float ms_act(float x) {
  float t = fminf(fmaxf(4.0f * x, 0.0f), 4.0f);
  return floorf(t + 0.5f) * 0.25f;
}

#define GLD16(g, l)                                                                           \
  __builtin_amdgcn_global_load_lds((__attribute__((address_space(1))) void*)(const void*)(g), \
                                   (__attribute__((address_space(3))) void*)(l), 16, 0, 0)

// ---------------------------------------------------------------------------
// Prep: split Wq/Wk/Wv into hi/lo bf16 planes [Wq;Wk;Wv], zero kv accumulator.
__global__ __launch_bounds__(256) void split_w_kernel(
    const float* __restrict__ Wq, const float* __restrict__ Wk, const float* __restrict__ Wv,
    unsigned short* __restrict__ Whi, unsigned short* __restrict__ Wlo, float* __restrict__ kv) {
  const int tid = threadIdx.x;
  const int w = blockIdx.y;
  const float* W = (w == 0) ? Wq : (w == 1) ? Wk : Wv;
  const size_t base = (size_t)w * 1048576u;
  const size_t i = (size_t)(blockIdx.x * 256 + tid) * 4;
  float4 v = *(const float4*)&W[i];
  float vv[4] = {v.x, v.y, v.z, v.w};
  unsigned short h4[4], l4[4];
#pragma unroll
  for (int j = 0; j < 4; ++j) {
    unsigned short hi = f2bf(vv[j]);
    h4[j] = hi;
    l4[j] = f2bf(vv[j] - bf2f(hi));
  }
  *(uint2*)&Whi[base + i] = make_uint2((unsigned)h4[0] | ((unsigned)h4[1] << 16),
                                       (unsigned)h4[2] | ((unsigned)h4[3] << 16));
  *(uint2*)&Wlo[base + i] = make_uint2((unsigned)l4[0] | ((unsigned)l4[1] << 16),
                                       (unsigned)l4[2] | ((unsigned)l4[3] << 16));
  if (w == 0 && blockIdx.x < 64) {
    ((float4*)kv)[blockIdx.x * 256 + tid] = make_float4(0.f, 0.f, 0.f, 0.f);
  }
}

// ---------------------------------------------------------------------------
__global__ __launch_bounds__(256) void act_x_kernel(const float* __restrict__ x,
                                                    unsigned short* __restrict__ xs,
                                                    long long n4) {
  long long i = (long long)blockIdx.x * 256 + threadIdx.x;
  const long long stride = (long long)gridDim.x * 256;
  for (; i < n4; i += stride) {
    float4 v = ((const float4*)x)[i];
    unsigned int lo = (unsigned)f2bf(ms_act(v.x)) | ((unsigned)f2bf(ms_act(v.y)) << 16);
    unsigned int hi = (unsigned)f2bf(ms_act(v.z)) | ((unsigned)f2bf(ms_act(v.w)) << 16);
    ((uint2*)xs)[i] = make_uint2(lo, hi);
  }
}

// ---------------------------------------------------------------------------
// C = A @ (Bh+Bl)^T. A: [65536, K=1024] bf16, row stride lda. B rows K-contig (1024).
// N = NCB*128 (B rows 0..N-1). QUANT=1: C (bf16) = ms_act(C), buffer picked per 1024-col
// bank (C0 for cols 0..1023, C1 for 1024..2047), ldc=1024. QUANT=0: Cf fp32, ldc=1024.
template <int QUANT, int LOG_NCB>
__global__ __launch_bounds__(512, 2) void gemm8(const unsigned short* __restrict__ A, size_t lda,
                                                const unsigned short* __restrict__ Bh,
                                                const unsigned short* __restrict__ Bl,
                                                unsigned short* __restrict__ C0,
                                                unsigned short* __restrict__ C1,
                                                float* __restrict__ Cf) {
  extern __shared__ unsigned short smem[];
  unsigned short* sA = smem;            // 4 bufs * 256*32 shorts = 64 KiB
  unsigned short* sBh = smem + 32768;   // 4 bufs * 128*32 shorts = 32 KiB
  unsigned short* sBl = smem + 49152;   // 32 KiB

  constexpr int NCB = 1 << LOG_NCB;
  const int chunk = (int)gridDim.x >> 3;
  const int gid = blockIdx.x;
  const int g2 = (gid & 7) * chunk + (gid >> 3);  // bijective XCD swizzle (nwg%8==0)
  const int rowb = g2 >> LOG_NCB;                 // col-blocks fastest -> A-panel L2 reuse
  const int cb = g2 & (NCB - 1);
  const size_t rowBase = (size_t)rowb * 256;
  const int colBase = cb * 128;

  const int tid = threadIdx.x;
  const int lane = tid & 63;
  const int wid = tid >> 6;
  const int wm = wid >> 1;  // 0..3 -> 64-row band
  const int wn = wid & 1;   // 0..1 -> 64-col band
  const int r15 = lane & 15;
  const int ks = lane >> 4;

  // ---- staging precompute (per thread: 4 gload_lds per slab) ----
  // Linear LDS dest; inverse-swizzled global source: slot' = slot ^ ((row>>1)&3).
  const int rl0 = tid >> 2;               // row 0..127 within op
  const int sswz = (tid >> 3) & 3;        // ((rl0)>>1)&3, same for rl0+128
  const int scol = ((tid & 3) ^ sswz) << 3;
  const unsigned short* pA0 = A + (rowBase + rl0) * lda + scol;
  const unsigned short* pA1 = pA0 + 128 * lda;
  const unsigned short* pBh = Bh + ((size_t)(colBase + rl0)) * 1024 + scol;
  const unsigned short* pBl = Bl + ((size_t)(colBase + rl0)) * 1024 + scol;

  auto stage = [&](int t) {
    const int buf = t & 3;
    const int k0 = t * 32;
    GLD16(pA0 + k0, sA + buf * 8192 + tid * 8);
    GLD16(pA1 + k0, sA + buf * 8192 + 4096 + tid * 8);
    GLD16(pBh + k0, sBh + buf * 4096 + tid * 8);
    GLD16(pBl + k0, sBl + buf * 4096 + tid * 8);
  };

  // ---- fragment read offsets (swizzled) ----
  const int slotr = (ks ^ ((r15 >> 1) & 3)) * 8;
  int offA[4], offB[4];
#pragma unroll
  for (int m = 0; m < 4; ++m) offA[m] = (wm * 64 + m * 16 + r15) * 32 + slotr;
#pragma unroll
  for (int n = 0; n < 4; ++n) offB[n] = (wn * 64 + n * 16 + r15) * 32 + slotr;

  f32x4 acc[4][4];
#pragma unroll
  for (int m = 0; m < 4; ++m)
#pragma unroll
    for (int n = 0; n < 4; ++n) acc[m][n] = (f32x4)(0.0f);

#define VMW(N) asm volatile("s_waitcnt vmcnt(" #N ")" ::: "memory")
#define PHASE(S, DOSTAGE)                                                                   \
  {                                                                                         \
    __syncthreads();                                                                        \
    if (DOSTAGE) stage((S) + 3);                                                            \
    const int buf = (S) & 3;                                                                \
    bf16x8 a[4], bh[4], bl[4];                                                              \
    _Pragma("unroll") for (int m = 0; m < 4; ++m)                                           \
        a[m] = *(const bf16x8*)&sA[buf * 8192 + offA[m]];                                   \
    _Pragma("unroll") for (int n = 0; n < 4; ++n) {                                         \
      bh[n] = *(const bf16x8*)&sBh[buf * 4096 + offB[n]];                                   \
      bl[n] = *(const bf16x8*)&sBl[buf * 4096 + offB[n]];                                   \
    }                                                                                       \
    asm volatile("s_waitcnt lgkmcnt(0)" ::: "memory");                                      \
    __builtin_amdgcn_sched_barrier(0);                                                      \
    __builtin_amdgcn_s_setprio(1);                                                          \
    _Pragma("unroll") for (int m = 0; m < 4; ++m)                                           \
      _Pragma("unroll") for (int n = 0; n < 4; ++n)                                         \
          acc[m][n] = __builtin_amdgcn_mfma_f32_16x16x32_bf16(a[m], bh[n], acc[m][n], 0, 0, 0); \
    _Pragma("unroll") for (int m = 0; m < 4; ++m)                                           \
      _Pragma("unroll") for (int n = 0; n < 4; ++n)                                         \
          acc[m][n] = __builtin_amdgcn_mfma_f32_16x16x32_bf16(a[m], bl[n], acc[m][n], 0, 0, 0); \
    __builtin_amdgcn_s_setprio(0);                                                          \
  }

  stage(0);
  stage(1);
  stage(2);
  for (int s = 0; s < 29; ++s) {
    VMW(8);  // slab s landed; slabs s+1,s+2 (8 loads) stay in flight
    PHASE(s, true);
  }
  VMW(8); PHASE(29, false);
  VMW(4); PHASE(30, false);
  VMW(0); PHASE(31, false);
#undef PHASE
#undef VMW

  // ---- epilogue ----
  const int rq = ks * 4;
  if (QUANT) {
    const int mat = colBase >> 10;
    unsigned short* Cq = mat ? C1 : C0;
    const int ccb = colBase & 1023;
#pragma unroll
    for (int m = 0; m < 4; ++m)
#pragma unroll
      for (int n = 0; n < 4; ++n) {
        const size_t row0 = rowBase + wm * 64 + m * 16 + rq;
        const int col = ccb + wn * 64 + n * 16 + r15;
#pragma unroll
        for (int j = 0; j < 4; ++j) Cq[(row0 + j) * 1024 + col] = f2bf(ms_act(acc[m][n][j]));
      }
  } else {
#pragma unroll
    for (int m = 0; m < 4; ++m)
#pragma unroll
      for (int n = 0; n < 4; ++n) {
        const size_t row0 = rowBase + wm * 64 + m * 16 + rq;
        const int col = colBase + wn * 64 + n * 16 + r15;
#pragma unroll
        for (int j = 0; j < 4; ++j) Cf[(row0 + j) * 1024 + col] = acc[m][n][j];
      }
  }
}

// ---------------------------------------------------------------------------
// kv[h,d,e] += sum_n k[n,h,d]*v[n,h,e]; exact fp32, atomicAdd order-independent.
__global__ __launch_bounds__(256) void kv_kernel(const unsigned short* __restrict__ K,
                                                 const unsigned short* __restrict__ V,
                                                 float* __restrict__ kv) {
  const int h = blockIdx.x;
  const long long n0 = (long long)blockIdx.y * 1024;
  const int tid = threadIdx.x;
  __shared__ unsigned short kss[16 * 64];
  __shared__ unsigned short vs[16 * 64];
  float acc[4][4] = {};
  const int db = (tid >> 4) * 4;
  const int eb = (tid & 15) * 4;
  const int idx = tid * 4;
  const int nl = idx >> 6, c = idx & 63;
  for (int s = 0; s < 64; ++s) {
    const long long nrow = n0 + s * 16 + nl;
    *(uint2*)&kss[idx] = *(const uint2*)&K[nrow * 1024 + h * 64 + c];
    *(uint2*)&vs[idx] = *(const uint2*)&V[nrow * 1024 + h * 64 + c];
    __syncthreads();
#pragma unroll
    for (int t = 0; t < 16; ++t) {
      float kd[4], ve[4];
#pragma unroll
      for (int i = 0; i < 4; ++i) kd[i] = bf2f(kss[t * 64 + db + i]);
#pragma unroll
      for (int j = 0; j < 4; ++j) ve[j] = bf2f(vs[t * 64 + eb + j]);
#pragma unroll
      for (int i = 0; i < 4; ++i)
#pragma unroll
        for (int j = 0; j < 4; ++j) acc[i][j] += kd[i] * ve[j];
    }
    __syncthreads();
  }
  float* base = kv + h * 4096;
#pragma unroll
  for (int i = 0; i < 4; ++i)
#pragma unroll
    for (int j = 0; j < 4; ++j) atomicAdd(&base[(db + i) * 64 + eb + j], acc[i][j]);
}

// ---------------------------------------------------------------------------
// Ut[j, h*64+d] = SCALE * sum_e kv[h,d,e] * Wp[j, h*64+e], split hi/lo bf16.
__global__ __launch_bounds__(256) void u_kernel(const float* __restrict__ kv,
                                                const float* __restrict__ Wp,
                                                unsigned short* __restrict__ Uhi,
                                                unsigned short* __restrict__ Ulo) {
  const int h = blockIdx.x;
  const int jb = blockIdx.y;
  const int tid = threadIdx.x;
  __shared__ float kvs[64 * 64];
  __shared__ float wps[64 * 64];
#pragma unroll
  for (int r = 0; r < 4; ++r) {
    const int f = tid + r * 256;
    ((float4*)kvs)[f] = ((const float4*)(kv + h * 4096))[f];
    ((float4*)wps)[f] =
        *(const float4*)&Wp[(size_t)(jb * 64 + (f >> 4)) * 1024 + h * 64 + (f & 15) * 4];
  }
  __syncthreads();
  const int db = (tid >> 4) * 4;
  const int jl = (tid & 15) * 4;
  float acc[4][4] = {};
  for (int e = 0; e < 64; ++e) {
    float kd[4], wj[4];
#pragma unroll
    for (int i = 0; i < 4; ++i) kd[i] = kvs[(db + i) * 64 + e];
#pragma unroll
    for (int j = 0; j < 4; ++j) wj[j] = wps[(jl + j) * 64 + e];
#pragma unroll
    for (int i = 0; i < 4; ++i)
#pragma unroll
      for (int j = 0; j < 4; ++j) acc[i][j] += kd[i] * wj[j];
  }
#pragma unroll
  for (int j = 0; j < 4; ++j)
#pragma unroll
    for (int i = 0; i < 4; ++i) {
      const float u = acc[i][j] * 0.25f;  // SCALE
      const unsigned short hi = f2bf(u);
      const unsigned short lo = f2bf(u - bf2f(hi));
      const size_t off = (size_t)(jb * 64 + jl + j) * 1024 + h * 64 + db + i;
      Uhi[off] = hi;
      Ulo[off] = lo;
    }
}

// ---------------------------------------------------------------------------
extern "C" void kernel_launch(void* const* d_in, const int* in_sizes, int n_in,
                              void* d_out, int out_size, void* d_ws, size_t ws_size,
                              hipStream_t stream) {
  const float* x = (const float*)d_in[0];
  const float* Wq = (const float*)d_in[1];
  const float* Wk = (const float*)d_in[2];
  const float* Wv = (const float*)d_in[3];
  const float* Wp = (const float*)d_in[4];
  float* out = (float*)d_out;

  char* ws = (char*)d_ws;
  const size_t NC2 = 134217728ull;  // 65536*1024 bf16 bytes
  unsigned short* xs = (unsigned short*)(ws);
  unsigned short* bufA = (unsigned short*)(ws + NC2);      // k, later reused for q
  unsigned short* bufB = (unsigned short*)(ws + 2 * NC2);  // v
  unsigned short* Whi = (unsigned short*)(ws + 3 * NC2);   // [3][1M] bf16
  unsigned short* Wlo = Whi + 3ull * 1048576;
  float* kvb = (float*)(ws + 3 * NC2 + 12582912ull);
  unsigned short* Uhi = (unsigned short*)(ws + 3 * NC2 + 12582912ull + 262144ull);
  unsigned short* Ulo = Uhi + 1048576;

  // allow 128 KiB dynamic LDS for the GEMM kernels (host-side, capture-safe)
  hipFuncSetAttribute((const void*)gemm8<1, 4>, hipFuncAttributeMaxDynamicSharedMemorySize,
                      131072);
  hipFuncSetAttribute((const void*)gemm8<1, 3>, hipFuncAttributeMaxDynamicSharedMemorySize,
                      131072);
  hipFuncSetAttribute((const void*)gemm8<0, 3>, hipFuncAttributeMaxDynamicSharedMemorySize,
                      131072);

  dim3 blk(256);
  split_w_kernel<<<dim3(1024, 3), blk, 0, stream>>>(Wq, Wk, Wv, Whi, Wlo, kvb);
  act_x_kernel<<<2048, blk, 0, stream>>>(x, xs, 16777216LL);
  // fused K|V projection: B rows 0..2047 = [Wk;Wv] planes; k->bufA, v->bufB
  gemm8<1, 4><<<4096, 512, 131072, stream>>>(xs, 1024, Whi + 1048576, Wlo + 1048576, bufA, bufB,
                                             nullptr);
  // kv = k^T v per head (exact)
  kv_kernel<<<dim3(16, 64), blk, 0, stream>>>(bufA, bufB, kvb);
  // q projection -> reuse bufA (k is dead)
  gemm8<1, 3><<<2048, 512, 131072, stream>>>(xs, 1024, Whi, Wlo, bufA, bufA, nullptr);
  // U = SCALE * kv @ Wp-slice, split hi/lo
  u_kernel<<<dim3(16, 16), blk, 0, stream>>>(kvb, Wp, Uhi, Ulo);
  // out = q @ U^T (fp32)
  gemm8<0, 3><<<2048, 512, 131072, stream>>>(bufA, 1024, Uhi, Ulo, nullptr, nullptr, out);
}

// Round 3
// 1541.199 us; speedup vs baseline: 1.1253x; 1.1253x over previous
//
#include <hip/hip_runtime.h>
#include <stdint.h>

// SpikeAttention on MI355X (gfx950).
// xs/q/k/v are ms_act-quantized (multiples of 0.25 in [0,1]) -> EXACT in bf16.
// Weights split hi+lo bf16, stored interleaved per row: W2[row][0:1024]=hi, [1024:2048]=lo.
// GEMM treats it as a single-plane K'=2048 problem with A[i,k'] = xs[i, k' & 1023]
// (A staging pointer wraps; no duplication in memory). Same accumulation class as r1/r2.
// kv = k^T v per head exact in fp32 -> atomicAdd deterministic.
// out = q @ U with U[j][2048] = hi|lo of SCALE * kv-folded Wp.
//
// GEMM schedule (r2 post-mortem: __syncthreads' implicit vmcnt(0) nullified the pipeline):
// BM=256 BN=256 BK=32, ring-of-4 LDS slabs (128 KiB), 8 waves, wave tile 128x64,
// raw s_barrier (1/slab) + explicit vmcnt(8) handshake BEFORE barrier, stage issued after,
// 2 sub-phases of 16 MFMA with lgkmcnt(0)+sched_barrier+setprio. Loads never drain <8
// in steady state (T3/T4), T2 swizzle kept (0 conflicts in r2), T5 setprio.

typedef __attribute__((ext_vector_type(8))) __bf16 bf16x8;
typedef __attribute__((ext_vector_type(4))) float f32x4;

__device__ __forceinline__ float bf2f(unsigned short u) {
  return __builtin_bit_cast(float, (unsigned int)u << 16);
}
__device__ __forceinline__ unsigned short f2bf(float f) {
  unsigned int u = __builtin_bit_cast(unsigned int, f);
  u += 0x7FFFu + ((u >> 16) & 1u);
  return (unsigned short)(u >> 16);
}
__device__ __forceinline__ float ms_act(float x) {
  float t = fminf(fmaxf(4.0f * x, 0.0f), 4.0f);
  return floorf(t + 0.5f) * 0.25f;
}

#define GLD16(g, l)                                                                           \
  __builtin_amdgcn_global_load_lds((__attribute__((address_space(1))) void*)(const void*)(g), \
                                   (__attribute__((address_space(3))) void*)(l), 16, 0, 0)

// ---------------------------------------------------------------------------
// Split Wq/Wk/Wv into interleaved hi|lo rows: W2 plane w = [1024][2048]. Zero kv.
__global__ __launch_bounds__(256) void split_w_kernel(
    const float* __restrict__ Wq, const float* __restrict__ Wk, const float* __restrict__ Wv,
    unsigned short* __restrict__ W2, float* __restrict__ kv) {
  const int tid = threadIdx.x;
  const int w = blockIdx.y;
  const float* W = (w == 0) ? Wq : (w == 1) ? Wk : Wv;
  unsigned short* P = W2 + (size_t)w * 2097152u;
  const int idx = blockIdx.x * 256 + tid;  // 0..262143
  const int row = idx >> 8;
  const int c0 = (idx & 255) * 4;
  float4 v = *(const float4*)&W[(size_t)row * 1024 + c0];
  float vv[4] = {v.x, v.y, v.z, v.w};
  unsigned short h4[4], l4[4];
#pragma unroll
  for (int j = 0; j < 4; ++j) {
    unsigned short hi = f2bf(vv[j]);
    h4[j] = hi;
    l4[j] = f2bf(vv[j] - bf2f(hi));
  }
  *(uint2*)&P[(size_t)row * 2048 + c0] =
      make_uint2((unsigned)h4[0] | ((unsigned)h4[1] << 16), (unsigned)h4[2] | ((unsigned)h4[3] << 16));
  *(uint2*)&P[(size_t)row * 2048 + 1024 + c0] =
      make_uint2((unsigned)l4[0] | ((unsigned)l4[1] << 16), (unsigned)l4[2] | ((unsigned)l4[3] << 16));
  if (w == 0 && blockIdx.x < 64) {
    ((float4*)kv)[blockIdx.x * 256 + tid] = make_float4(0.f, 0.f, 0.f, 0.f);
  }
}

// ---------------------------------------------------------------------------
__global__ __launch_bounds__(256) void act_x_kernel(const float* __restrict__ x,
                                                    unsigned short* __restrict__ xs,
                                                    long long n4) {
  long long i = (long long)blockIdx.x * 256 + threadIdx.x;
  const long long stride = (long long)gridDim.x * 256;
  for (; i < n4; i += stride) {
    float4 v = ((const float4*)x)[i];
    unsigned int lo = (unsigned)f2bf(ms_act(v.x)) | ((unsigned)f2bf(ms_act(v.y)) << 16);
    unsigned int hi = (unsigned)f2bf(ms_act(v.z)) | ((unsigned)f2bf(ms_act(v.w)) << 16);
    ((uint2*)xs)[i] = make_uint2(lo, hi);
  }
}

// ---------------------------------------------------------------------------
// C = A @ B2^T over K'=2048. A: [65536,1024] bf16 (k wraps mod 1024). B2 rows: [N][2048].
// BM=256, BN=256. QUANT=1: ms_act -> bf16, split across C0 (cols<1024) / C1. QUANT=0: fp32 Cf.
template <int QUANT, int LOG_NCB>
__global__ __launch_bounds__(512, 2) void gemm8(const unsigned short* __restrict__ A,
                                                const unsigned short* __restrict__ B2,
                                                unsigned short* __restrict__ C0,
                                                unsigned short* __restrict__ C1,
                                                float* __restrict__ Cf) {
  extern __shared__ unsigned short smem[];
  unsigned short* sA = smem;          // 4 bufs x 256x32 = 32768 shorts (64 KiB)
  unsigned short* sB = smem + 32768;  // 4 bufs x 256x32 = 32768 shorts (64 KiB)

  constexpr int NCB = 1 << LOG_NCB;
  const int chunk = (int)gridDim.x >> 3;
  const int gid = blockIdx.x;
  const int g2 = (gid & 7) * chunk + (gid >> 3);  // bijective XCD swizzle (nwg%8==0)
  const int rowb = g2 >> LOG_NCB;                 // col-blocks fastest -> A-panel L2 reuse
  const int cb = g2 & (NCB - 1);
  const size_t rowBase = (size_t)rowb * 256;
  const int colBase = cb * 256;

  const int tid = threadIdx.x;
  const int lane = tid & 63;
  const int wid = tid >> 6;  // 0..7
  const int wm = wid >> 2;   // 0..1 -> 128-row band
  const int wn = wid & 3;    // 0..3 -> 64-col band
  const int r15 = lane & 15;
  const int ks = lane >> 4;

  // ---- staging (per thread per slab: 2 A gloads + 2 B gloads, 16 B each) ----
  // Linear LDS dest; inverse-swizzled global source col: slot' = slot ^ ((row>>1)&3).
  const int rl0 = tid >> 2;          // 0..127
  const int sswz = (tid >> 3) & 3;   // ((rl0)>>1)&3 (same for rl0+128)
  const int scol = ((tid & 3) ^ sswz) << 3;
  const unsigned short* pA0 = A + (rowBase + rl0) * 1024 + scol;
  const unsigned short* pA1 = pA0 + 128 * 1024;
  const unsigned short* pB0 = B2 + (size_t)(colBase + rl0) * 2048 + scol;
  const unsigned short* pB1 = pB0 + 128 * 2048;
  const int ldst = tid * 8;

  auto stage_a = [&](int t) {
    const int buf = (t & 3) * 8192;
    const int ka = (t * 32) & 1023;  // A wraps: hi-pass then lo-pass
    GLD16(pA0 + ka, sA + buf + ldst);
    GLD16(pA1 + ka, sA + buf + 4096 + ldst);
  };
  auto stage_b = [&](int t) {
    const int buf = (t & 3) * 8192;
    const int kb = t * 32;
    GLD16(pB0 + kb, sB + buf + ldst);
    GLD16(pB1 + kb, sB + buf + 4096 + ldst);
  };

  // ---- fragment read offsets (swizzled; r2-verified formula) ----
  const int slotr = (ks ^ ((r15 >> 1) & 3)) * 8;
  int offA[8], offB[4];
#pragma unroll
  for (int m = 0; m < 8; ++m) offA[m] = (wm * 128 + m * 16 + r15) * 32 + slotr;
#pragma unroll
  for (int n = 0; n < 4; ++n) offB[n] = (wn * 64 + n * 16 + r15) * 32 + slotr;

  f32x4 acc[8][4];
#pragma unroll
  for (int m = 0; m < 8; ++m)
#pragma unroll
    for (int n = 0; n < 4; ++n) acc[m][n] = (f32x4)(0.0f);

#define VMW(N) asm volatile("s_waitcnt vmcnt(" #N ")" ::: "memory")
#define SLAB(S, WN, DS)                                                                          \
  {                                                                                              \
    VMW(WN); /* own slab-S loads landed (others' guaranteed after barrier) */                    \
    __builtin_amdgcn_s_barrier();                                                                \
    asm volatile("" ::: "memory");                                                               \
    if (DS) stage_a((S) + 3);                                                                    \
    const int buf_ = ((S)&3) * 8192;                                                             \
    bf16x8 bfr[4];                                                                               \
    _Pragma("unroll") for (int n = 0; n < 4; ++n) bfr[n] =                                       \
        *(const bf16x8*)&sB[buf_ + offB[n]];                                                     \
    {                                                                                            \
      bf16x8 aP[4];                                                                              \
      _Pragma("unroll") for (int mi = 0; mi < 4; ++mi) aP[mi] =                                  \
          *(const bf16x8*)&sA[buf_ + offA[mi]];                                                  \
      asm volatile("s_waitcnt lgkmcnt(0)" ::: "memory");                                         \
      __builtin_amdgcn_sched_barrier(0);                                                         \
      __builtin_amdgcn_s_setprio(1);                                                             \
      _Pragma("unroll") for (int mi = 0; mi < 4; ++mi) _Pragma("unroll") for (int n = 0; n < 4;  \
                                                                              ++n) acc[mi][n] =  \
          __builtin_amdgcn_mfma_f32_16x16x32_bf16(aP[mi], bfr[n], acc[mi][n], 0, 0, 0);          \
      __builtin_amdgcn_s_setprio(0);                                                             \
    }                                                                                            \
    if (DS) stage_b((S) + 3);                                                                    \
    {                                                                                            \
      bf16x8 aP[4];                                                                              \
      _Pragma("unroll") for (int mi = 0; mi < 4; ++mi) aP[mi] =                                  \
          *(const bf16x8*)&sA[buf_ + offA[4 + mi]];                                              \
      asm volatile("s_waitcnt lgkmcnt(0)" ::: "memory");                                         \
      __builtin_amdgcn_sched_barrier(0);                                                         \
      __builtin_amdgcn_s_setprio(1);                                                             \
      _Pragma("unroll") for (int mi = 0; mi < 4; ++mi) _Pragma("unroll") for (int n = 0; n < 4;  \
                                                                              ++n)               \
          acc[4 + mi][n] =                                                                       \
          __builtin_amdgcn_mfma_f32_16x16x32_bf16(aP[mi], bfr[n], acc[4 + mi][n], 0, 0, 0);      \
      __builtin_amdgcn_s_setprio(0);                                                             \
    }                                                                                            \
  }

  // prologue: 3 slabs in flight (12 loads)
  stage_a(0); stage_b(0);
  stage_a(1); stage_b(1);
  stage_a(2); stage_b(2);
  for (int s = 0; s < 61; ++s) {
    SLAB(s, 8, true);  // steady: in-flight 8..12, never drained below 8
  }
  SLAB(61, 8, false);
  SLAB(62, 4, false);
  SLAB(63, 0, false);
#undef SLAB
#undef VMW

  // ---- epilogue (C/D mapping r2-verified) ----
  const int rq = ks * 4;
  if (QUANT) {
    const int mat = colBase >> 10;
    unsigned short* Cq = mat ? C1 : C0;
    const int cb0 = (colBase & 1023) + wn * 64;
#pragma unroll
    for (int m = 0; m < 8; ++m)
#pragma unroll
      for (int n = 0; n < 4; ++n) {
        const size_t row0 = rowBase + wm * 128 + m * 16 + rq;
        const int col = cb0 + n * 16 + r15;
#pragma unroll
        for (int j = 0; j < 4; ++j) Cq[(row0 + j) * 1024 + col] = f2bf(ms_act(acc[m][n][j]));
      }
  } else {
#pragma unroll
    for (int m = 0; m < 8; ++m)
#pragma unroll
      for (int n = 0; n < 4; ++n) {
        const size_t row0 = rowBase + wm * 128 + m * 16 + rq;
        const int col = colBase + wn * 64 + n * 16 + r15;
#pragma unroll
        for (int j = 0; j < 4; ++j) Cf[(row0 + j) * 1024 + col] = acc[m][n][j];
      }
  }
}

// ---------------------------------------------------------------------------
// kv[h,d,e] += sum_n k[n,h,d]*v[n,h,e]; exact fp32, atomicAdd order-independent.
__global__ __launch_bounds__(256) void kv_kernel(const unsigned short* __restrict__ K,
                                                 const unsigned short* __restrict__ V,
                                                 float* __restrict__ kv) {
  const int h = blockIdx.x;
  const long long n0 = (long long)blockIdx.y * 1024;
  const int tid = threadIdx.x;
  __shared__ unsigned short kss[16 * 64];
  __shared__ unsigned short vs[16 * 64];
  float acc[4][4] = {};
  const int db = (tid >> 4) * 4;
  const int eb = (tid & 15) * 4;
  const int idx = tid * 4;
  const int nl = idx >> 6, c = idx & 63;
  for (int s = 0; s < 64; ++s) {
    const long long nrow = n0 + s * 16 + nl;
    *(uint2*)&kss[idx] = *(const uint2*)&K[nrow * 1024 + h * 64 + c];
    *(uint2*)&vs[idx] = *(const uint2*)&V[nrow * 1024 + h * 64 + c];
    __syncthreads();
#pragma unroll
    for (int t = 0; t < 16; ++t) {
      float kd[4], ve[4];
#pragma unroll
      for (int i = 0; i < 4; ++i) kd[i] = bf2f(kss[t * 64 + db + i]);
#pragma unroll
      for (int j = 0; j < 4; ++j) ve[j] = bf2f(vs[t * 64 + eb + j]);
#pragma unroll
      for (int i = 0; i < 4; ++i)
#pragma unroll
        for (int j = 0; j < 4; ++j) acc[i][j] += kd[i] * ve[j];
    }
    __syncthreads();
  }
  float* base = kv + h * 4096;
#pragma unroll
  for (int i = 0; i < 4; ++i)
#pragma unroll
    for (int j = 0; j < 4; ++j) atomicAdd(&base[(db + i) * 64 + eb + j], acc[i][j]);
}

// ---------------------------------------------------------------------------
// U2[j][0:1024]=hi, [1024:2048]=lo of SCALE * sum_e kv[h,d,e]*Wp[j,h*64+e] at col h*64+d.
__global__ __launch_bounds__(256) void u_kernel(const float* __restrict__ kv,
                                                const float* __restrict__ Wp,
                                                unsigned short* __restrict__ U2) {
  const int h = blockIdx.x;
  const int jb = blockIdx.y;
  const int tid = threadIdx.x;
  __shared__ float kvs[64 * 64];
  __shared__ float wps[64 * 64];
#pragma unroll
  for (int r = 0; r < 4; ++r) {
    const int f = tid + r * 256;
    ((float4*)kvs)[f] = ((const float4*)(kv + h * 4096))[f];
    ((float4*)wps)[f] =
        *(const float4*)&Wp[(size_t)(jb * 64 + (f >> 4)) * 1024 + h * 64 + (f & 15) * 4];
  }
  __syncthreads();
  const int db = (tid >> 4) * 4;
  const int jl = (tid & 15) * 4;
  float acc[4][4] = {};
  for (int e = 0; e < 64; ++e) {
    float kd[4], wj[4];
#pragma unroll
    for (int i = 0; i < 4; ++i) kd[i] = kvs[(db + i) * 64 + e];
#pragma unroll
    for (int j = 0; j < 4; ++j) wj[j] = wps[(jl + j) * 64 + e];
#pragma unroll
    for (int i = 0; i < 4; ++i)
#pragma unroll
      for (int j = 0; j < 4; ++j) acc[i][j] += kd[i] * wj[j];
  }
#pragma unroll
  for (int j = 0; j < 4; ++j)
#pragma unroll
    for (int i = 0; i < 4; ++i) {
      const float u = acc[i][j] * 0.25f;  // SCALE
      const unsigned short hi = f2bf(u);
      const unsigned short lo = f2bf(u - bf2f(hi));
      const size_t off = (size_t)(jb * 64 + jl + j) * 2048 + h * 64 + db + i;
      U2[off] = hi;
      U2[off + 1024] = lo;
    }
}

// ---------------------------------------------------------------------------
extern "C" void kernel_launch(void* const* d_in, const int* in_sizes, int n_in,
                              void* d_out, int out_size, void* d_ws, size_t ws_size,
                              hipStream_t stream) {
  const float* x = (const float*)d_in[0];
  const float* Wq = (const float*)d_in[1];
  const float* Wk = (const float*)d_in[2];
  const float* Wv = (const float*)d_in[3];
  const float* Wp = (const float*)d_in[4];
  float* out = (float*)d_out;

  char* ws = (char*)d_ws;
  const size_t NC2 = 134217728ull;  // 65536*1024 bf16 bytes
  unsigned short* xs = (unsigned short*)(ws);
  unsigned short* bufA = (unsigned short*)(ws + NC2);      // k, later reused for q
  unsigned short* bufB = (unsigned short*)(ws + 2 * NC2);  // v
  unsigned short* W2 = (unsigned short*)(ws + 3 * NC2);    // 3 planes x [1024][2048]
  float* kvb = (float*)(ws + 3 * NC2 + 12582912ull);
  unsigned short* U2 = (unsigned short*)(ws + 3 * NC2 + 12582912ull + 262144ull);  // [1024][2048]

  hipFuncSetAttribute((const void*)gemm8<1, 3>, hipFuncAttributeMaxDynamicSharedMemorySize,
                      131072);
  hipFuncSetAttribute((const void*)gemm8<1, 2>, hipFuncAttributeMaxDynamicSharedMemorySize,
                      131072);
  hipFuncSetAttribute((const void*)gemm8<0, 2>, hipFuncAttributeMaxDynamicSharedMemorySize,
                      131072);

  dim3 blk(256);
  split_w_kernel<<<dim3(1024, 3), blk, 0, stream>>>(Wq, Wk, Wv, W2, kvb);
  act_x_kernel<<<2048, blk, 0, stream>>>(x, xs, 16777216LL);
  // fused K|V projection: B rows 0..2047 = [Wk;Wv] planes; k->bufA, v->bufB
  gemm8<1, 3><<<2048, 512, 131072, stream>>>(xs, W2 + 2097152, bufA, bufB, nullptr);
  // kv = k^T v per head (exact)
  kv_kernel<<<dim3(16, 64), blk, 0, stream>>>(bufA, bufB, kvb);
  // q projection -> reuse bufA (k is dead)
  gemm8<1, 2><<<1024, 512, 131072, stream>>>(xs, W2, bufA, bufA, nullptr);
  // U = SCALE * kv @ Wp-slice, hi|lo interleaved
  u_kernel<<<dim3(16, 16), blk, 0, stream>>>(kvb, Wp, U2);
  // out = q @ U^T (fp32)
  gemm8<0, 2><<<1024, 512, 131072, stream>>>(bufA, U2, nullptr, nullptr, out);
}